// Round 10
// baseline (575.821 us; speedup 1.0000x reference)
//
#include <hip/hip_runtime.h>
#include <hip/hip_fp16.h>

#define BLOCK 256
#define PAD 16   // one counter per 64B cache line

// sliced layout: addr(row,col) = ((col>>5)*N + row)*32 + (col&31)
// each 32-col slice is a contiguous 3.2MB region (fp16, N=50k)

// ---------------- typed vector load/store helpers ----------------
__device__ inline float4 ld4f(const float* p) { return *(const float4*)p; }
__device__ inline float4 ld4f(const __half* p) {
    uint2 u = *(const uint2*)p;
    __half2 a = *reinterpret_cast<__half2*>(&u.x);
    __half2 b = *reinterpret_cast<__half2*>(&u.y);
    float2 fa = __half22float2(a), fb = __half22float2(b);
    return make_float4(fa.x, fa.y, fb.x, fb.y);
}
__device__ inline void st4f(float* p, float4 v) { *(float4*)p = v; }
__device__ inline void st4f(__half* p, float4 v) {
    __half2 a = __floats2half2_rn(v.x, v.y);
    __half2 b = __floats2half2_rn(v.z, v.w);
    uint2 u;
    u.x = *reinterpret_cast<unsigned*>(&a);
    u.y = *reinterpret_cast<unsigned*>(&b);
    *(uint2*)p = u;
}
__device__ inline void st8f(float* p, const float f[8]) {
    *(float4*)p       = make_float4(f[0], f[1], f[2], f[3]);
    *(float4*)(p + 4) = make_float4(f[4], f[5], f[6], f[7]);
}
__device__ inline void st8f(__half* p, const float f[8]) {
    union { __half2 h[4]; float4 v; } u;
    u.h[0] = __floats2half2_rn(f[0], f[1]);
    u.h[1] = __floats2half2_rn(f[2], f[3]);
    u.h[2] = __floats2half2_rn(f[4], f[5]);
    u.h[3] = __floats2half2_rn(f[6], f[7]);
    *(float4*)p = u.v;
}
__device__ inline void ld2v(const float* p, float* f) {
    float2 v = *(const float2*)p; f[0] = v.x; f[1] = v.y;
}
__device__ inline void ld2v(const __half* p, float* f) {
    float2 v = __half22float2(*(const __half2*)p); f[0] = v.x; f[1] = v.y;
}
__device__ inline void ld8v(const float* p, float* f) {
    float4 a = *(const float4*)p, b = *(const float4*)(p + 4);
    f[0]=a.x; f[1]=a.y; f[2]=a.z; f[3]=a.w; f[4]=b.x; f[5]=b.y; f[6]=b.z; f[7]=b.w;
}
__device__ inline void ld8v(const __half* p, float* f) {
    float4 r = *(const float4*)p;
    const __half2* h = (const __half2*)&r;
#pragma unroll
    for (int j = 0; j < 4; ++j) {
        float2 fj = __half22float2(h[j]);
        f[2*j] = fj.x; f[2*j+1] = fj.y;
    }
}
__device__ inline float edgeW(int2 er) {
    return __half2float(__ushort_as_half((unsigned short)(er.y & 0xffff)));
}

// ---------------- degree (padded counters, int atomics) ----------------
__global__ void deg_kernel(const int* __restrict__ src, const int* __restrict__ dst,
                           int* __restrict__ degOpad, int* __restrict__ degIpad, int E) {
    int e = blockIdx.x * blockDim.x + threadIdx.x;
    if (e < E) {
        atomicAdd(&degOpad[src[e] * PAD], 1);
        atomicAdd(&degIpad[dst[e] * PAD], 1);
    }
}

// ---------------- hierarchical exclusive scan of degI ----------------
__global__ void scan_local(const int* __restrict__ degIpad, int* __restrict__ rowStart,
                           int* __restrict__ blockSums, int N) {
    __shared__ int tmp[1024];
    int tid = threadIdx.x;
    int i = blockIdx.x * 1024 + tid;
    int v = (i < N) ? degIpad[i * PAD] : 0;
    tmp[tid] = v;
    __syncthreads();
    for (int off = 1; off < 1024; off <<= 1) {
        int t = (tid >= off) ? tmp[tid - off] : 0;
        __syncthreads();
        tmp[tid] += t;
        __syncthreads();
    }
    if (i < N) rowStart[i] = tmp[tid] - v;
    if (tid == 0) blockSums[blockIdx.x] = tmp[1023];
}

__global__ void scan_sums(int* __restrict__ blockSums, int nb) {
    __shared__ int tmp[64];
    int tid = threadIdx.x;
    int v = (tid < nb) ? blockSums[tid] : 0;
    tmp[tid] = v;
    __syncthreads();
    for (int off = 1; off < 64; off <<= 1) {
        int t = (tid >= off) ? tmp[tid - off] : 0;
        __syncthreads();
        tmp[tid] += t;
        __syncthreads();
    }
    if (tid < nb) blockSums[tid] = tmp[tid] - v;
}

__global__ void scan_add_norm(int* __restrict__ rowStart, const int* __restrict__ blockSums,
                              int* __restrict__ cursorPad,
                              const int* __restrict__ degOpad, const int* __restrict__ degIpad,
                              float* __restrict__ normO, float* __restrict__ normI,
                              int N, int E) {
    int i = blockIdx.x * blockDim.x + threadIdx.x;
    if (i < N) {
        int r = rowStart[i] + blockSums[i >> 10];
        rowStart[i] = r;
        cursorPad[i * PAD] = r;
        normO[i] = rsqrtf(fmaxf((float)degOpad[i * PAD], 1.0f));
        normI[i] = rsqrtf(fmaxf((float)degIpad[i * PAD], 1.0f));
    }
    if (i == N) rowStart[N] = E;
}

// ---------------- permute edges into dst-sorted order: one 8B record ----------------
__global__ void permute_kernel(const int* __restrict__ src, const int* __restrict__ dst,
                               const float* __restrict__ efet, int* __restrict__ cursorPad,
                               int2* __restrict__ edges, int E) {
    int e = blockIdx.x * blockDim.x + threadIdx.x;
    if (e < E) {
        int d = dst[e];
        int p = atomicAdd(&cursorPad[d * PAD], 1);
        int2 er;
        er.x = src[e];
        er.y = (int)__half_as_ushort(__float2half(efet[e]));
        edges[p] = er;
    }
}

// ---------------- generic CSR gather-agg, 4 cols/thread, linear layout ----------------
template <int D, typename IT, typename OT>
__global__ void agg_kernel(const IT* __restrict__ in, OT* __restrict__ out,
                           const int* __restrict__ rowStart, const int2* __restrict__ edges,
                           int useW,
                           const float* __restrict__ srcScale,
                           const float* __restrict__ dstScale,
                           const float* __restrict__ bias,
                           int N, int relu) {
    constexpr int TPN = D / 4;
    int gid = blockIdx.x * blockDim.x + threadIdx.x;
    int v = gid / TPN;
    int c4 = (gid % TPN) * 4;
    if (v >= N) return;
    int beg = rowStart[v], end = rowStart[v + 1];
    float ax = 0.f, ay = 0.f, az = 0.f, aw = 0.f;
    const IT* base = in + c4;

    int j = beg;
    for (; j + 4 <= end; j += 4) {
        int2 e0 = edges[j + 0], e1 = edges[j + 1], e2 = edges[j + 2], e3 = edges[j + 3];
        float w0 = useW ? edgeW(e0) : 1.f;
        float w1 = useW ? edgeW(e1) : 1.f;
        float w2 = useW ? edgeW(e2) : 1.f;
        float w3 = useW ? edgeW(e3) : 1.f;
        if (srcScale) {
            w0 *= srcScale[e0.x]; w1 *= srcScale[e1.x];
            w2 *= srcScale[e2.x]; w3 *= srcScale[e3.x];
        }
        float4 x0 = ld4f(base + (size_t)e0.x * D);
        float4 x1 = ld4f(base + (size_t)e1.x * D);
        float4 x2 = ld4f(base + (size_t)e2.x * D);
        float4 x3 = ld4f(base + (size_t)e3.x * D);
        ax += x0.x * w0; ay += x0.y * w0; az += x0.z * w0; aw += x0.w * w0;
        ax += x1.x * w1; ay += x1.y * w1; az += x1.z * w1; aw += x1.w * w1;
        ax += x2.x * w2; ay += x2.y * w2; az += x2.z * w2; aw += x2.w * w2;
        ax += x3.x * w3; ay += x3.y * w3; az += x3.z * w3; aw += x3.w * w3;
    }
    for (; j < end; ++j) {
        int2 er = edges[j];
        float w = useW ? edgeW(er) : 1.f;
        if (srcScale) w *= srcScale[er.x];
        float4 val = ld4f(base + (size_t)er.x * D);
        ax += val.x * w; ay += val.y * w; az += val.z * w; aw += val.w * w;
    }
    if (dstScale) {
        float sc = dstScale[v];
        ax = ax * sc + bias[c4 + 0];
        ay = ay * sc + bias[c4 + 1];
        az = az * sc + bias[c4 + 2];
        aw = aw * sc + bias[c4 + 3];
    }
    if (relu) {
        ax = fmaxf(ax, 0.f); ay = fmaxf(ay, 0.f);
        az = fmaxf(az, 0.f); aw = fmaxf(aw, 0.f);
    }
    st4f(out + (size_t)v * D + c4, make_float4(ax, ay, az, aw));
}

// ---------------- XCD-pinned sliced agg (fp16, sliced layout in AND out) --------
// Work unit = (slice, 64-node stripe). Blocks claim units from per-slice atomic
// queues, preferring the queue of their OWN XCD (s_getreg XCC_ID) -> per-XCD L2
// working set is one contiguous 3.2MB slice. Fallback scan guarantees every unit
// is processed exactly once regardless of the (undefined) block->XCD mapping.
__global__ __launch_bounds__(256) void sagg_kernel(
    const __half* __restrict__ in, __half* __restrict__ out,
    const int* __restrict__ rowStart, const int2* __restrict__ edges,
    int useW,
    const float* __restrict__ dstScale,  // null -> skip scale+bias
    const float* __restrict__ bias,
    int N, int relu,
    int* __restrict__ q, int NS, int nStripes)
{
    __shared__ int sh[2];
    if (threadIdx.x == 0) {
        // hwreg(HW_REG_XCC_ID=20, offset=0, size=32) -> imm = 20 | (31<<11) = 63508
        int xcc = __builtin_amdgcn_s_getreg(63508) & 7;
        int sl = -1, stripe = -1;
        int s0 = xcc % NS;
        for (int t = 0; t < NS; ++t) {
            int s = s0 + t; if (s >= NS) s -= NS;
            int pos = atomicAdd(&q[s * 16], 1);
            if (pos < nStripes) { sl = s; stripe = pos; break; }
        }
        sh[0] = sl; sh[1] = stripe;
    }
    __syncthreads();
    int sl = sh[0], stripe = sh[1];
    if (sl < 0) return;
    int t = threadIdx.x;
    int v = stripe * 64 + (t >> 2);
    if (v >= N) return;
    int sub = (t & 3) * 8;                      // 8 cols per thread
    const __half* base = in + (size_t)sl * N * 32 + sub;

    int beg = rowStart[v], end = rowStart[v + 1];
    float a[8];
#pragma unroll
    for (int k = 0; k < 8; ++k) a[k] = 0.f;

    int j = beg;
    for (; j + 4 <= end; j += 4) {
        int2 er[4];
#pragma unroll
        for (int p = 0; p < 4; ++p) er[p] = edges[j + p];
        float xf[4][8];
#pragma unroll
        for (int p = 0; p < 4; ++p) ld8v(base + (size_t)er[p].x * 32, xf[p]);
#pragma unroll
        for (int p = 0; p < 4; ++p) {
            float w = useW ? edgeW(er[p]) : 1.f;
#pragma unroll
            for (int k = 0; k < 8; ++k) a[k] += xf[p][k] * w;
        }
    }
    for (; j < end; ++j) {
        int2 er = edges[j];
        float w = useW ? edgeW(er) : 1.f;
        float xv[8];
        ld8v(base + (size_t)er.x * 32, xv);
#pragma unroll
        for (int k = 0; k < 8; ++k) a[k] += xv[k] * w;
    }
    if (dstScale) {
        float sc = dstScale[v];
        int col0 = sl * 32 + sub;
#pragma unroll
        for (int k = 0; k < 8; ++k) a[k] = a[k] * sc + bias[col0 + k];
    }
    if (relu) {
#pragma unroll
        for (int k = 0; k < 8; ++k) a[k] = fmaxf(a[k], 0.f);
    }
    st8f(out + (size_t)sl * N * 32 + (size_t)v * 32 + sub, a);
}

// ---------------- tiled register-blocked GEMM, optional sliced A/C layouts -------
template <int KT, int RPT, int TN, bool ASL, bool CSL, typename AT, typename OT>
__global__ __launch_bounds__(256) void gemm_tiled(
    const AT* __restrict__ A, const float* __restrict__ W,
    const float* __restrict__ rowScaleIn,
    const float* __restrict__ rowScaleOut,
    const float* __restrict__ bias,
    OT* __restrict__ C, int N, int K1, int relu)
{
    constexpr int NC8 = TN / 8;
    constexpr int RT  = 256 / NC8;
    constexpr int TM  = RT * RPT;
    constexpr int AFPT = TM * KT / 256;
    constexpr int WF4  = KT * TN / 1024;
    static_assert(AFPT == 2 || AFPT == 8, "unexpected AFPT");

    __shared__ float Alds[KT][TM];
    __shared__ float Wlds[KT][TN];

    const int t    = threadIdx.x;
    const int cg   = t % NC8;
    const int rt   = t / NC8;
    const int c0   = cg * 8;
    const int row0 = blockIdx.x * TM;

    const int arow   = t % TM;
    const int akb    = (t / TM) * AFPT;
    const int arow_g = row0 + arow;
    float rsc = 1.0f;
    if (rowScaleIn && arow_g < N) rsc = rowScaleIn[arow_g];

    float acc[RPT][8];
#pragma unroll
    for (int r = 0; r < RPT; ++r)
#pragma unroll
        for (int j = 0; j < 8; ++j) acc[r][j] = 0.f;

    for (int k0 = 0; k0 < K1; k0 += KT) {
        float av[AFPT];
        if (arow_g < N) {
            const AT* ag;
            int kk0 = k0 + akb;
            if constexpr (ASL) ag = A + ((size_t)(kk0 >> 5) * N + arow_g) * 32 + (kk0 & 31);
            else               ag = A + (size_t)arow_g * K1 + kk0;
            if constexpr (AFPT == 8) ld8v(ag, av);
            else                     ld2v(ag, av);
        } else {
#pragma unroll
            for (int j = 0; j < AFPT; ++j) av[j] = 0.f;
        }
#pragma unroll
        for (int j = 0; j < AFPT; ++j)
            Alds[akb + j][arow] = av[j] * rsc;

        {
            const float4* wg = (const float4*)(W + (size_t)k0 * TN);
            float4* wl = (float4*)&Wlds[0][0];
#pragma unroll
            for (int j = 0; j < WF4; ++j) wl[j * 256 + t] = wg[j * 256 + t];
        }
        __syncthreads();

#pragma unroll
        for (int kk = 0; kk < KT; ++kk) {
            float a[RPT];
            if constexpr (RPT == 4) {
                float4 avv = *(const float4*)&Alds[kk][rt * 4];
                a[0] = avv.x; a[1] = avv.y; a[2] = avv.z; a[3] = avv.w;
            } else if constexpr (RPT == 2) {
                float2 avv = *(const float2*)&Alds[kk][rt * 2];
                a[0] = avv.x; a[1] = avv.y;
            } else {
                a[0] = Alds[kk][rt];
            }
            float4 w0 = *(const float4*)&Wlds[kk][c0];
            float4 w1 = *(const float4*)&Wlds[kk][c0 + 4];
#pragma unroll
            for (int r = 0; r < RPT; ++r) {
                acc[r][0] += a[r] * w0.x; acc[r][1] += a[r] * w0.y;
                acc[r][2] += a[r] * w0.z; acc[r][3] += a[r] * w0.w;
                acc[r][4] += a[r] * w1.x; acc[r][5] += a[r] * w1.y;
                acc[r][6] += a[r] * w1.z; acc[r][7] += a[r] * w1.w;
            }
        }
        __syncthreads();
    }

#pragma unroll
    for (int r = 0; r < RPT; ++r) {
        int row_g = row0 + rt * RPT + r;
        if (row_g >= N) continue;
        float f[8];
        if (rowScaleOut) {
            float sc = rowScaleOut[row_g];
#pragma unroll
            for (int j = 0; j < 8; ++j) f[j] = acc[r][j] * sc + bias[c0 + j];
        } else {
#pragma unroll
            for (int j = 0; j < 8; ++j) f[j] = acc[r][j];
        }
        if (relu) {
#pragma unroll
            for (int j = 0; j < 8; ++j) f[j] = fmaxf(f[j], 0.f);
        }
        OT* cp;
        if constexpr (CSL) cp = C + ((size_t)(c0 >> 5) * N + row_g) * 32 + (c0 & 31);
        else               cp = C + (size_t)row_g * TN + c0;
        st8f(cp, f);
    }
}

// ---------------- naive GEMM (K2=4 layer) ----------------
template <typename AT>
__global__ void gemm_naive(const AT* __restrict__ A, const float* __restrict__ W,
                           const float* __restrict__ rowScaleIn,
                           float* __restrict__ C, int N, int K1, int K2) {
    int gid = blockIdx.x * blockDim.x + threadIdx.x;
    int col = gid % K2;
    int row = gid / K2;
    if (row >= N) return;
    const AT* a = A + (size_t)row * K1;
    float acc = 0.0f;
    for (int k = 0; k < K1; ++k) acc += (float)a[k] * W[k * K2 + col];
    if (rowScaleIn) acc *= rowScaleIn[row];
    C[gid] = acc;
}

static inline int nblk(long n) { return (int)((n + BLOCK - 1) / BLOCK); }

extern "C" void kernel_launch(void* const* d_in, const int* in_sizes, int n_in,
                              void* d_out, int out_size, void* d_ws, size_t ws_size,
                              hipStream_t stream) {
    const float* x    = (const float*)d_in[0];
    const float* efet = (const float*)d_in[1];
    const int*   src  = (const int*)d_in[2];
    const int*   dst  = (const int*)d_in[3];
    const float* W1 = (const float*)d_in[4];  const float* b1 = (const float*)d_in[5];
    const float* W2 = (const float*)d_in[6];  const float* b2 = (const float*)d_in[7];
    const float* W3 = (const float*)d_in[8];  const float* b3 = (const float*)d_in[9];
    const float* W4 = (const float*)d_in[10]; const float* b4 = (const float*)d_in[11];
    const float* W5 = (const float*)d_in[12]; const float* b5 = (const float*)d_in[13];
    float* out = (float*)d_out;

    const int N = in_sizes[0] / 16;
    const int E = in_sizes[2];
    const int NB1024 = (N + 1023) / 1024;
    const int nStripes = (N + 63) / 64;

    // ---- workspace layout ----
    float* fws = (float*)d_ws;
    size_t o = 0;
    auto alloc = [&](size_t nf) { float* p = fws + o; o += (nf + 3) & ~(size_t)3; return p; };
    float*  normO     = alloc(N);
    float*  normI     = alloc(N);
    int*    rowStart  = (int*)alloc(N + 1);
    int*    blockSums = (int*)alloc(64);
    int2*   edges     = (int2*)alloc(2 * (size_t)E);        // 8B per edge
    // zeroed region: queues + deg counters (one memset)
    int*    qarr      = (int*)alloc(5 * 128);               // 5 dispatches x 8 counters x 16 pad
    int*    degOpad   = (int*)alloc((size_t)PAD * N);
    int*    degIpad   = (int*)alloc((size_t)PAD * N);
    int*    cursorPad = (int*)alloc((size_t)PAD * N);
    __half* bufA      = (__half*)alloc(128 * (size_t)N);    // 256N halves
    __half* bufB      = (__half*)alloc(128 * (size_t)N);    // 256N halves
    __half* bufC      = (__half*)alloc(64 * (size_t)N);     // 128N halves
    float*  t5f       = (float*)bufA;                       // layer-5 fp32 temp (aliases bufA)

    // ---- degrees + CSR build ----
    hipMemsetAsync(qarr, 0, (5 * 128 + 2 * (size_t)PAD * N) * sizeof(int), stream);
    deg_kernel<<<nblk(E), BLOCK, 0, stream>>>(src, dst, degOpad, degIpad, E);
    scan_local<<<NB1024, 1024, 0, stream>>>(degIpad, rowStart, blockSums, N);
    scan_sums<<<1, 64, 0, stream>>>(blockSums, NB1024);
    scan_add_norm<<<nblk(N + 1), BLOCK, 0, stream>>>(rowStart, blockSums, cursorPad,
                                                     degOpad, degIpad, normO, normI, N, E);
    permute_kernel<<<nblk(E), BLOCK, 0, stream>>>(src, dst, efet, cursorPad, edges, E);

    // ---- Layer 1: agg16 (linear) -> GEMM 16->256 (C sliced) -> ewa256 sliced ----
    agg_kernel<16, float, __half><<<nblk((long)N * 4), BLOCK, 0, stream>>>(
        x, bufC, rowStart, edges, 0, normO, nullptr, nullptr, N, 0);
    gemm_tiled<16, 4, 256, false, true, __half, __half><<<(N + 31) / 32, 256, 0, stream>>>(
        bufC, W1, nullptr, normI, b1, bufA, N, 16, 1);
    sagg_kernel<<<8 * nStripes, 256, 0, stream>>>(
        bufA, bufB, rowStart, edges, 1, nullptr, nullptr, N, 1, qarr + 0 * 128, 8, nStripes);  // h1=bufB

    // ---- Layer 2: GEMM 256->128 (A,C sliced), gc128 sliced, ewa128 sliced ----
    gemm_tiled<32, 4, 128, true, true, __half, __half><<<(N + 63) / 64, 256, 0, stream>>>(
        bufB, W2, normO, nullptr, nullptr, bufA, N, 256, 0);
    sagg_kernel<<<4 * nStripes, 256, 0, stream>>>(
        bufA, bufC, rowStart, edges, 0, normI, b2, N, 1, qarr + 1 * 128, 4, nStripes);
    sagg_kernel<<<4 * nStripes, 256, 0, stream>>>(
        bufC, bufB, rowStart, edges, 1, nullptr, nullptr, N, 1, qarr + 2 * 128, 4, nStripes);  // h2=bufB

    // ---- Layer 3: GEMM 128->64 (A,C sliced), gc64 sliced, ewa64 sliced ----
    gemm_tiled<32, 2, 64, true, true, __half, __half><<<(N + 63) / 64, 256, 0, stream>>>(
        bufB, W3, normO, nullptr, nullptr, bufA, N, 128, 0);
    sagg_kernel<<<2 * nStripes, 256, 0, stream>>>(
        bufA, bufC, rowStart, edges, 0, normI, b3, N, 1, qarr + 3 * 128, 2, nStripes);
    sagg_kernel<<<2 * nStripes, 256, 0, stream>>>(
        bufC, bufB, rowStart, edges, 1, nullptr, nullptr, N, 1, qarr + 4 * 128, 2, nStripes);  // h3=bufB

    // ---- Layer 4: GEMM 64->32 (A sliced, C linear), agg32 linear -> h4 ----
    gemm_tiled<32, 1, 32, true, false, __half, __half><<<(N + 63) / 64, 256, 0, stream>>>(
        bufB, W4, normO, nullptr, nullptr, bufA, N, 64, 0);
    agg_kernel<32, __half, __half><<<nblk((long)N * 8), BLOCK, 0, stream>>>(
        bufA, bufB, rowStart, edges, 0, nullptr, normI, b4, N, 1);                             // h4=bufB

    // ---- Layer 5: GEMM 32->4 (fp32 out), agg4 -> out ----
    gemm_naive<__half><<<nblk((long)N * 4), BLOCK, 0, stream>>>(
        bufB, W5, normO, t5f, N, 32, 4);
    agg_kernel<4, float, float><<<nblk((long)N), BLOCK, 0, stream>>>(
        t5f, out, rowStart, edges, 0, nullptr, normI, b5, N, 0);
}

// Round 11
// 566.333 us; speedup vs baseline: 1.0168x; 1.0168x over previous
//
#include <hip/hip_runtime.h>
#include <hip/hip_fp16.h>

#define BLOCK 256
#define PAD 16   // one counter per 64B cache line

// ---------------- helpers ----------------
__device__ inline void st4f(__half* p, float4 v) {
    __half2 a = __floats2half2_rn(v.x, v.y);
    __half2 b = __floats2half2_rn(v.z, v.w);
    uint2 u;
    u.x = *reinterpret_cast<unsigned*>(&a);
    u.y = *reinterpret_cast<unsigned*>(&b);
    *(uint2*)p = u;
}
__device__ inline void st4f(float* p, float4 v) { *(float4*)p = v; }
__device__ inline void st8f(float* p, const float f[8]) {
    *(float4*)p       = make_float4(f[0], f[1], f[2], f[3]);
    *(float4*)(p + 4) = make_float4(f[4], f[5], f[6], f[7]);
}
__device__ inline void st8f(__half* p, const float f[8]) {
    union { __half2 h[4]; float4 v; } u;
    u.h[0] = __floats2half2_rn(f[0], f[1]);
    u.h[1] = __floats2half2_rn(f[2], f[3]);
    u.h[2] = __floats2half2_rn(f[4], f[5]);
    u.h[3] = __floats2half2_rn(f[6], f[7]);
    *(float4*)p = u.v;
}
__device__ inline void ld2v(const __half* p, float* f) {
    float2 v = __half22float2(*(const __half2*)p); f[0] = v.x; f[1] = v.y;
}
__device__ inline void ld8v(const __half* p, float* f) {
    float4 r = *(const float4*)p;
    const __half2* h = (const __half2*)&r;
#pragma unroll
    for (int j = 0; j < 4; ++j) {
        float2 fj = __half22float2(h[j]);
        f[2*j] = fj.x; f[2*j+1] = fj.y;
    }
}
__device__ inline float4 ld4f(const float* p) { return *(const float4*)p; }
__device__ inline float edgeW(int2 er) {
    return __half2float(__ushort_as_half((unsigned short)(er.y & 0xffff)));
}

// ---------------- degree (padded counters, int atomics) ----------------
__global__ void deg_kernel(const int* __restrict__ src, const int* __restrict__ dst,
                           int* __restrict__ degOpad, int* __restrict__ degIpad, int E) {
    int e = blockIdx.x * blockDim.x + threadIdx.x;
    if (e < E) {
        atomicAdd(&degOpad[src[e] * PAD], 1);
        atomicAdd(&degIpad[dst[e] * PAD], 1);
    }
}

// ---------------- hierarchical exclusive scan of degI ----------------
__global__ void scan_local(const int* __restrict__ degIpad, int* __restrict__ rowStart,
                           int* __restrict__ blockSums, int N) {
    __shared__ int tmp[1024];
    int tid = threadIdx.x;
    int i = blockIdx.x * 1024 + tid;
    int v = (i < N) ? degIpad[i * PAD] : 0;
    tmp[tid] = v;
    __syncthreads();
    for (int off = 1; off < 1024; off <<= 1) {
        int t = (tid >= off) ? tmp[tid - off] : 0;
        __syncthreads();
        tmp[tid] += t;
        __syncthreads();
    }
    if (i < N) rowStart[i] = tmp[tid] - v;
    if (tid == 0) blockSums[blockIdx.x] = tmp[1023];
}

__global__ void scan_sums(int* __restrict__ blockSums, int nb) {
    __shared__ int tmp[64];
    int tid = threadIdx.x;
    int v = (tid < nb) ? blockSums[tid] : 0;
    tmp[tid] = v;
    __syncthreads();
    for (int off = 1; off < 64; off <<= 1) {
        int t = (tid >= off) ? tmp[tid - off] : 0;
        __syncthreads();
        tmp[tid] += t;
        __syncthreads();
    }
    if (tid < nb) blockSums[tid] = tmp[tid] - v;
}

__global__ void scan_add_norm(int* __restrict__ rowStart, const int* __restrict__ blockSums,
                              int* __restrict__ cursorPad,
                              const int* __restrict__ degOpad, const int* __restrict__ degIpad,
                              float* __restrict__ normO, float* __restrict__ normI,
                              int N, int E) {
    int i = blockIdx.x * blockDim.x + threadIdx.x;
    if (i < N) {
        int r = rowStart[i] + blockSums[i >> 10];
        rowStart[i] = r;
        cursorPad[i * PAD] = r;
        normO[i] = rsqrtf(fmaxf((float)degOpad[i * PAD], 1.0f));
        normI[i] = rsqrtf(fmaxf((float)degIpad[i * PAD], 1.0f));
    }
    if (i == N) rowStart[N] = E;
}

// ---------------- block-local degree sort: nodes in each 1024-chunk ordered by deg ----
// Waves in the agg kernels then process near-equal-degree nodes (kills max-deg tax).
__global__ void sort_local(const int* __restrict__ degIpad, int* __restrict__ sortedNodes,
                           int N) {
    __shared__ int hist[64];
    __shared__ int cur[64];
    int t = threadIdx.x;
    int i = blockIdx.x * 1024 + t;
    if (t < 64) hist[t] = 0;
    __syncthreads();
    int d = -1;
    if (i < N) {
        d = degIpad[i * PAD];
        if (d > 63) d = 63;
        atomicAdd(&hist[d], 1);
    }
    __syncthreads();
    if (t == 0) {
        int acc = 0;
        for (int k = 0; k < 64; ++k) { cur[k] = acc; acc += hist[k]; }
    }
    __syncthreads();
    if (d >= 0) {
        int pos = atomicAdd(&cur[d], 1);
        sortedNodes[blockIdx.x * 1024 + pos] = i;
    }
}

// ---------------- x: fp32 -> fp16 with normO folded in ----------------
__global__ void cvt_x(const float* __restrict__ x, const float* __restrict__ normO,
                      __half* __restrict__ xh, int N) {
    int gid = blockIdx.x * blockDim.x + threadIdx.x;
    int v = gid >> 2;
    int c = (gid & 3) * 4;
    if (v >= N) return;
    float4 f = ld4f(x + (size_t)v * 16 + c);
    float w = normO[v];
    f.x *= w; f.y *= w; f.z *= w; f.w *= w;
    st4f(xh + (size_t)v * 16 + c, f);
}

// ---------------- permute edges into dst-sorted order: one 8B record ----------------
__global__ void permute_kernel(const int* __restrict__ src, const int* __restrict__ dst,
                               const float* __restrict__ efet, int* __restrict__ cursorPad,
                               int2* __restrict__ edges, int E) {
    int e = blockIdx.x * blockDim.x + threadIdx.x;
    if (e < E) {
        int d = dst[e];
        int p = atomicAdd(&cursorPad[d * PAD], 1);
        int2 er;
        er.x = src[e];
        er.y = (int)__half_as_ushort(__float2half(efet[e]));
        edges[p] = er;
    }
}

// ---------------- CSR gather-agg, 8 cols/thread, unroll 8, degree-sorted order ------
template <int D>
__global__ __launch_bounds__(256) void agg8_kernel(
    const __half* __restrict__ in, __half* __restrict__ out,
    const int* __restrict__ rowStart, const int2* __restrict__ edges,
    const int* __restrict__ sortedNodes,
    int useW,
    const float* __restrict__ dstScale,   // null -> skip scale+bias
    const float* __restrict__ bias,
    int N, int relu) {
    constexpr int TPN = D / 8;
    int gid = blockIdx.x * blockDim.x + threadIdx.x;
    int u = gid / TPN;
    int c8 = (gid % TPN) * 8;
    if (u >= N) return;
    int v = sortedNodes[u];
    int beg = rowStart[v], end = rowStart[v + 1];
    float a[8];
#pragma unroll
    for (int k = 0; k < 8; ++k) a[k] = 0.f;
    const __half* base = in + c8;

    int j = beg;
    for (; j + 8 <= end; j += 8) {
        int2 er[8];
#pragma unroll
        for (int q = 0; q < 8; ++q) er[q] = edges[j + q];
        float xf[8][8];
#pragma unroll
        for (int q = 0; q < 8; ++q) ld8v(base + (size_t)er[q].x * D, xf[q]);
#pragma unroll
        for (int q = 0; q < 8; ++q) {
            float w = useW ? edgeW(er[q]) : 1.f;
#pragma unroll
            for (int k = 0; k < 8; ++k) a[k] += xf[q][k] * w;
        }
    }
    if (j + 4 <= end) {
        int2 er[4];
#pragma unroll
        for (int q = 0; q < 4; ++q) er[q] = edges[j + q];
        float xf[4][8];
#pragma unroll
        for (int q = 0; q < 4; ++q) ld8v(base + (size_t)er[q].x * D, xf[q]);
#pragma unroll
        for (int q = 0; q < 4; ++q) {
            float w = useW ? edgeW(er[q]) : 1.f;
#pragma unroll
            for (int k = 0; k < 8; ++k) a[k] += xf[q][k] * w;
        }
        j += 4;
    }
    for (; j < end; ++j) {
        int2 er = edges[j];
        float w = useW ? edgeW(er) : 1.f;
        float xv[8];
        ld8v(base + (size_t)er.x * D, xv);
#pragma unroll
        for (int k = 0; k < 8; ++k) a[k] += xv[k] * w;
    }
    if (dstScale) {
        float sc = dstScale[v];
#pragma unroll
        for (int k = 0; k < 8; ++k) a[k] = a[k] * sc + bias[c8 + k];
    }
    if (relu) {
#pragma unroll
        for (int k = 0; k < 8; ++k) a[k] = fmaxf(a[k], 0.f);
    }
    st8f(out + (size_t)v * D + c8, a);
}

// ---------------- final agg: D=4, fp32, degree-sorted ----------------
__global__ void agg4_kernel(const float* __restrict__ in, float* __restrict__ out,
                            const int* __restrict__ rowStart, const int2* __restrict__ edges,
                            const int* __restrict__ sortedNodes,
                            const float* __restrict__ dstScale, const float* __restrict__ bias,
                            int N) {
    int u = blockIdx.x * blockDim.x + threadIdx.x;
    if (u >= N) return;
    int v = sortedNodes[u];
    int beg = rowStart[v], end = rowStart[v + 1];
    float ax = 0.f, ay = 0.f, az = 0.f, aw = 0.f;
    for (int j = beg; j < end; ++j) {
        int2 er = edges[j];
        float4 val = ld4f(in + (size_t)er.x * 4);
        ax += val.x; ay += val.y; az += val.z; aw += val.w;
    }
    float sc = dstScale[v];
    ax = ax * sc + bias[0];
    ay = ay * sc + bias[1];
    az = az * sc + bias[2];
    aw = aw * sc + bias[3];
    st4f(out + (size_t)v * 4, make_float4(ax, ay, az, aw));
}

// ---------------- tiled register-blocked GEMM (linear layouts) ----------------
template <int KT, int RPT, int TN, typename AT, typename OT>
__global__ __launch_bounds__(256) void gemm_tiled(
    const AT* __restrict__ A, const float* __restrict__ W,
    const float* __restrict__ rowScaleIn,
    const float* __restrict__ rowScaleOut,
    const float* __restrict__ bias,
    OT* __restrict__ C, int N, int K1, int relu)
{
    constexpr int NC8 = TN / 8;
    constexpr int RT  = 256 / NC8;
    constexpr int TM  = RT * RPT;
    constexpr int AFPT = TM * KT / 256;
    constexpr int WF4  = KT * TN / 1024;
    static_assert(AFPT == 2 || AFPT == 8, "unexpected AFPT");

    __shared__ float Alds[KT][TM];
    __shared__ float Wlds[KT][TN];

    const int t    = threadIdx.x;
    const int cg   = t % NC8;
    const int rt   = t / NC8;
    const int c0   = cg * 8;
    const int row0 = blockIdx.x * TM;

    const int arow   = t % TM;
    const int akb    = (t / TM) * AFPT;
    const int arow_g = row0 + arow;
    float rsc = 1.0f;
    if (rowScaleIn && arow_g < N) rsc = rowScaleIn[arow_g];

    float acc[RPT][8];
#pragma unroll
    for (int r = 0; r < RPT; ++r)
#pragma unroll
        for (int j = 0; j < 8; ++j) acc[r][j] = 0.f;

    for (int k0 = 0; k0 < K1; k0 += KT) {
        float av[AFPT];
        if (arow_g < N) {
            const AT* ag = A + (size_t)arow_g * K1 + k0 + akb;
            if constexpr (AFPT == 8) ld8v(ag, av);
            else                     ld2v(ag, av);
        } else {
#pragma unroll
            for (int j = 0; j < AFPT; ++j) av[j] = 0.f;
        }
#pragma unroll
        for (int j = 0; j < AFPT; ++j)
            Alds[akb + j][arow] = av[j] * rsc;

        {
            const float4* wg = (const float4*)(W + (size_t)k0 * TN);
            float4* wl = (float4*)&Wlds[0][0];
#pragma unroll
            for (int j = 0; j < WF4; ++j) wl[j * 256 + t] = wg[j * 256 + t];
        }
        __syncthreads();

#pragma unroll
        for (int kk = 0; kk < KT; ++kk) {
            float a[RPT];
            if constexpr (RPT == 4) {
                float4 avv = *(const float4*)&Alds[kk][rt * 4];
                a[0] = avv.x; a[1] = avv.y; a[2] = avv.z; a[3] = avv.w;
            } else if constexpr (RPT == 2) {
                float2 avv = *(const float2*)&Alds[kk][rt * 2];
                a[0] = avv.x; a[1] = avv.y;
            } else {
                a[0] = Alds[kk][rt];
            }
            float4 w0 = *(const float4*)&Wlds[kk][c0];
            float4 w1 = *(const float4*)&Wlds[kk][c0 + 4];
#pragma unroll
            for (int r = 0; r < RPT; ++r) {
                acc[r][0] += a[r] * w0.x; acc[r][1] += a[r] * w0.y;
                acc[r][2] += a[r] * w0.z; acc[r][3] += a[r] * w0.w;
                acc[r][4] += a[r] * w1.x; acc[r][5] += a[r] * w1.y;
                acc[r][6] += a[r] * w1.z; acc[r][7] += a[r] * w1.w;
            }
        }
        __syncthreads();
    }

#pragma unroll
    for (int r = 0; r < RPT; ++r) {
        int row_g = row0 + rt * RPT + r;
        if (row_g >= N) continue;
        float f[8];
        if (rowScaleOut) {
            float sc = rowScaleOut[row_g];
#pragma unroll
            for (int j = 0; j < 8; ++j) f[j] = acc[r][j] * sc + bias[c0 + j];
        } else {
#pragma unroll
            for (int j = 0; j < 8; ++j) f[j] = acc[r][j];
        }
        if (relu) {
#pragma unroll
            for (int j = 0; j < 8; ++j) f[j] = fmaxf(f[j], 0.f);
        }
        st8f(C + (size_t)row_g * TN + c0, f);
    }
}

// ---------------- naive GEMM (K2=4 layer) ----------------
__global__ void gemm_naive(const __half* __restrict__ A, const float* __restrict__ W,
                           const float* __restrict__ rowScaleIn,
                           float* __restrict__ C, int N, int K1, int K2) {
    int gid = blockIdx.x * blockDim.x + threadIdx.x;
    int col = gid % K2;
    int row = gid / K2;
    if (row >= N) return;
    const __half* a = A + (size_t)row * K1;
    float acc = 0.0f;
    for (int k = 0; k < K1; ++k) acc += (float)a[k] * W[k * K2 + col];
    if (rowScaleIn) acc *= rowScaleIn[row];
    C[gid] = acc;
}

static inline int nblk(long n) { return (int)((n + BLOCK - 1) / BLOCK); }

extern "C" void kernel_launch(void* const* d_in, const int* in_sizes, int n_in,
                              void* d_out, int out_size, void* d_ws, size_t ws_size,
                              hipStream_t stream) {
    const float* x    = (const float*)d_in[0];
    const float* efet = (const float*)d_in[1];
    const int*   src  = (const int*)d_in[2];
    const int*   dst  = (const int*)d_in[3];
    const float* W1 = (const float*)d_in[4];  const float* b1 = (const float*)d_in[5];
    const float* W2 = (const float*)d_in[6];  const float* b2 = (const float*)d_in[7];
    const float* W3 = (const float*)d_in[8];  const float* b3 = (const float*)d_in[9];
    const float* W4 = (const float*)d_in[10]; const float* b4 = (const float*)d_in[11];
    const float* W5 = (const float*)d_in[12]; const float* b5 = (const float*)d_in[13];
    float* out = (float*)d_out;

    const int N = in_sizes[0] / 16;
    const int E = in_sizes[2];
    const int NB1024 = (N + 1023) / 1024;

    // ---- workspace layout ----
    float* fws = (float*)d_ws;
    size_t o = 0;
    auto alloc = [&](size_t nf) { float* p = fws + o; o += (nf + 3) & ~(size_t)3; return p; };
    float*  normO       = alloc(N);
    float*  normI       = alloc(N);
    int*    rowStart    = (int*)alloc(N + 1);
    int*    blockSums   = (int*)alloc(64);
    int*    sortedNodes = (int*)alloc(N);
    int2*   edges       = (int2*)alloc(2 * (size_t)E);     // 8B per edge
    int*    degOpad     = (int*)alloc((size_t)PAD * N);    // zeroed
    int*    degIpad     = (int*)alloc((size_t)PAD * N);    // zeroed
    int*    cursorPad   = (int*)alloc((size_t)PAD * N);    // init by scan_add_norm
    __half* xh          = (__half*)alloc(8 * (size_t)N);   // N x 16 halves
    __half* bufA        = (__half*)alloc(128 * (size_t)N); // 256N halves
    __half* bufB        = (__half*)alloc(128 * (size_t)N); // 256N halves
    __half* bufC        = (__half*)alloc(64 * (size_t)N);  // 128N halves
    float*  t5f         = (float*)bufA;                    // layer-5 fp32 temp (aliases bufA)

    // ---- degrees + CSR build + degree sort ----
    hipMemsetAsync(degOpad, 0, 2 * (size_t)PAD * N * sizeof(int), stream);
    deg_kernel<<<nblk(E), BLOCK, 0, stream>>>(src, dst, degOpad, degIpad, E);
    scan_local<<<NB1024, 1024, 0, stream>>>(degIpad, rowStart, blockSums, N);
    scan_sums<<<1, 64, 0, stream>>>(blockSums, NB1024);
    scan_add_norm<<<nblk(N + 1), BLOCK, 0, stream>>>(rowStart, blockSums, cursorPad,
                                                     degOpad, degIpad, normO, normI, N, E);
    sort_local<<<NB1024, 1024, 0, stream>>>(degIpad, sortedNodes, N);
    cvt_x<<<nblk((long)N * 4), BLOCK, 0, stream>>>(x, normO, xh, N);
    permute_kernel<<<nblk(E), BLOCK, 0, stream>>>(src, dst, efet, cursorPad, edges, E);

    // ---- Layer 1: agg16 (fp16, normO pre-folded) -> GEMM 16->256 -> ewa256 ----
    agg8_kernel<16><<<nblk((long)N * 2), BLOCK, 0, stream>>>(
        xh, bufC, rowStart, edges, sortedNodes, 0, nullptr, nullptr, N, 0);
    gemm_tiled<16, 4, 256, __half, __half><<<(N + 31) / 32, 256, 0, stream>>>(
        bufC, W1, nullptr, normI, b1, bufA, N, 16, 1);
    agg8_kernel<256><<<nblk((long)N * 32), BLOCK, 0, stream>>>(
        bufA, bufB, rowStart, edges, sortedNodes, 1, nullptr, nullptr, N, 1);   // h1 = bufB

    // ---- Layer 2: GEMM 256->128, gc128, ewa128 ----
    gemm_tiled<32, 4, 128, __half, __half><<<(N + 63) / 64, 256, 0, stream>>>(
        bufB, W2, normO, nullptr, nullptr, bufA, N, 256, 0);
    agg8_kernel<128><<<nblk((long)N * 16), BLOCK, 0, stream>>>(
        bufA, bufC, rowStart, edges, sortedNodes, 0, normI, b2, N, 1);
    agg8_kernel<128><<<nblk((long)N * 16), BLOCK, 0, stream>>>(
        bufC, bufB, rowStart, edges, sortedNodes, 1, nullptr, nullptr, N, 1);   // h2 = bufB

    // ---- Layer 3: GEMM 128->64, gc64, ewa64 ----
    gemm_tiled<32, 2, 64, __half, __half><<<(N + 63) / 64, 256, 0, stream>>>(
        bufB, W3, normO, nullptr, nullptr, bufA, N, 128, 0);
    agg8_kernel<64><<<nblk((long)N * 8), BLOCK, 0, stream>>>(
        bufA, bufC, rowStart, edges, sortedNodes, 0, normI, b3, N, 1);
    agg8_kernel<64><<<nblk((long)N * 8), BLOCK, 0, stream>>>(
        bufC, bufB, rowStart, edges, sortedNodes, 1, nullptr, nullptr, N, 1);   // h3 = bufB

    // ---- Layer 4: GEMM 64->32, gc32 -> h4 ----
    gemm_tiled<32, 1, 32, __half, __half><<<(N + 63) / 64, 256, 0, stream>>>(
        bufB, W4, normO, nullptr, nullptr, bufA, N, 64, 0);
    agg8_kernel<32><<<nblk((long)N * 4), BLOCK, 0, stream>>>(
        bufA, bufB, rowStart, edges, sortedNodes, 0, normI, b4, N, 1);          // h4 = bufB

    // ---- Layer 5: GEMM 32->4 (fp32 out), agg4 -> out ----
    gemm_naive<<<nblk((long)N * 4), BLOCK, 0, stream>>>(
        bufB, W5, normO, t5f, N, 32, 4);
    agg4_kernel<<<nblk((long)N), BLOCK, 0, stream>>>(
        t5f, out, rowStart, edges, sortedNodes, normI, b5, N);
}

// Round 12
// 524.760 us; speedup vs baseline: 1.0973x; 1.0792x over previous
//
#include <hip/hip_runtime.h>
#include <hip/hip_fp16.h>

#define BLOCK 256
#define PAD 16   // one counter per 64B cache line

typedef _Float16 h2v __attribute__((ext_vector_type(2)));

// ---------------- helpers ----------------
__device__ inline void st4f(__half* p, float4 v) {
    __half2 a = __floats2half2_rn(v.x, v.y);
    __half2 b = __floats2half2_rn(v.z, v.w);
    uint2 u;
    u.x = *reinterpret_cast<unsigned*>(&a);
    u.y = *reinterpret_cast<unsigned*>(&b);
    *(uint2*)p = u;
}
__device__ inline void st4f(float* p, float4 v) { *(float4*)p = v; }
__device__ inline void st8f(float* p, const float f[8]) {
    *(float4*)p       = make_float4(f[0], f[1], f[2], f[3]);
    *(float4*)(p + 4) = make_float4(f[4], f[5], f[6], f[7]);
}
__device__ inline void st8f(__half* p, const float f[8]) {
    union { __half2 h[4]; float4 v; } u;
    u.h[0] = __floats2half2_rn(f[0], f[1]);
    u.h[1] = __floats2half2_rn(f[2], f[3]);
    u.h[2] = __floats2half2_rn(f[4], f[5]);
    u.h[3] = __floats2half2_rn(f[6], f[7]);
    *(float4*)p = u.v;
}
__device__ inline void ld2v(const __half* p, float* f) {
    float2 v = __half22float2(*(const __half2*)p); f[0] = v.x; f[1] = v.y;
}
__device__ inline void ld8v(const __half* p, float* f) {
    float4 r = *(const float4*)p;
    const __half2* h = (const __half2*)&r;
#pragma unroll
    for (int j = 0; j < 4; ++j) {
        float2 fj = __half22float2(h[j]);
        f[2*j] = fj.x; f[2*j+1] = fj.y;
    }
}
__device__ inline float4 ld4f(const float* p) { return *(const float4*)p; }
__device__ inline float edgeW(int2 er) {
    return __half2float(__ushort_as_half((unsigned short)(er.y & 0xffff)));
}
__device__ inline h2v packh2(float a, float b) {
    h2v r; r.x = (_Float16)a; r.y = (_Float16)b; return r;
}

// ---------------- degree (padded counters, int atomics) ----------------
__global__ void deg_kernel(const int* __restrict__ src, const int* __restrict__ dst,
                           int* __restrict__ degOpad, int* __restrict__ degIpad, int E) {
    int e = blockIdx.x * blockDim.x + threadIdx.x;
    if (e < E) {
        atomicAdd(&degOpad[src[e] * PAD], 1);
        atomicAdd(&degIpad[dst[e] * PAD], 1);
    }
}

// ---------------- hierarchical exclusive scan of degI ----------------
__global__ void scan_local(const int* __restrict__ degIpad, int* __restrict__ rowStart,
                           int* __restrict__ blockSums, int N) {
    __shared__ int tmp[1024];
    int tid = threadIdx.x;
    int i = blockIdx.x * 1024 + tid;
    int v = (i < N) ? degIpad[i * PAD] : 0;
    tmp[tid] = v;
    __syncthreads();
    for (int off = 1; off < 1024; off <<= 1) {
        int t = (tid >= off) ? tmp[tid - off] : 0;
        __syncthreads();
        tmp[tid] += t;
        __syncthreads();
    }
    if (i < N) rowStart[i] = tmp[tid] - v;
    if (tid == 0) blockSums[blockIdx.x] = tmp[1023];
}

__global__ void scan_sums(int* __restrict__ blockSums, int nb) {
    __shared__ int tmp[64];
    int tid = threadIdx.x;
    int v = (tid < nb) ? blockSums[tid] : 0;
    tmp[tid] = v;
    __syncthreads();
    for (int off = 1; off < 64; off <<= 1) {
        int t = (tid >= off) ? tmp[tid - off] : 0;
        __syncthreads();
        tmp[tid] += t;
        __syncthreads();
    }
    if (tid < nb) blockSums[tid] = tmp[tid] - v;
}

__global__ void scan_add_norm(int* __restrict__ rowStart, const int* __restrict__ blockSums,
                              int* __restrict__ cursorPad,
                              const int* __restrict__ degOpad, const int* __restrict__ degIpad,
                              float* __restrict__ normO, float* __restrict__ normI,
                              int N, int E) {
    int i = blockIdx.x * blockDim.x + threadIdx.x;
    if (i < N) {
        int r = rowStart[i] + blockSums[i >> 10];
        rowStart[i] = r;
        cursorPad[i * PAD] = r;
        normO[i] = rsqrtf(fmaxf((float)degOpad[i * PAD], 1.0f));
        normI[i] = rsqrtf(fmaxf((float)degIpad[i * PAD], 1.0f));
    }
    if (i == N) rowStart[N] = E;
}

// ---------------- x: fp32 -> fp16 with normO folded in ----------------
__global__ void cvt_x(const float* __restrict__ x, const float* __restrict__ normO,
                      __half* __restrict__ xh, int N) {
    int gid = blockIdx.x * blockDim.x + threadIdx.x;
    int v = gid >> 2;
    int c = (gid & 3) * 4;
    if (v >= N) return;
    float4 f = ld4f(x + (size_t)v * 16 + c);
    float w = normO[v];
    f.x *= w; f.y *= w; f.z *= w; f.w *= w;
    st4f(xh + (size_t)v * 16 + c, f);
}

// ---------------- permute edges into dst-sorted order: one 8B record ----------------
__global__ void permute_kernel(const int* __restrict__ src, const int* __restrict__ dst,
                               const float* __restrict__ efet, int* __restrict__ cursorPad,
                               int2* __restrict__ edges, int E) {
    int e = blockIdx.x * blockDim.x + threadIdx.x;
    if (e < E) {
        int d = dst[e];
        int p = atomicAdd(&cursorPad[d * PAD], 1);
        int2 er;
        er.x = src[e];
        er.y = (int)__half_as_ushort(__float2half(efet[e]));
        edges[p] = er;
    }
}

// ---------------- CSR gather-agg, 8 cols/thread, unroll 8 (fp16) ----------------
template <int D>
__global__ __launch_bounds__(256) void agg8_kernel(
    const __half* __restrict__ in, __half* __restrict__ out,
    const int* __restrict__ rowStart, const int2* __restrict__ edges,
    int useW,
    const float* __restrict__ dstScale,   // null -> skip scale+bias
    const float* __restrict__ bias,
    int N, int relu) {
    constexpr int TPN = D / 8;
    int gid = blockIdx.x * blockDim.x + threadIdx.x;
    int v = gid / TPN;
    int c8 = (gid % TPN) * 8;
    if (v >= N) return;
    int beg = rowStart[v], end = rowStart[v + 1];
    float a[8];
#pragma unroll
    for (int k = 0; k < 8; ++k) a[k] = 0.f;
    const __half* base = in + c8;

    int j = beg;
    for (; j + 8 <= end; j += 8) {
        int2 er[8];
#pragma unroll
        for (int q = 0; q < 8; ++q) er[q] = edges[j + q];
        float xf[8][8];
#pragma unroll
        for (int q = 0; q < 8; ++q) ld8v(base + (size_t)er[q].x * D, xf[q]);
#pragma unroll
        for (int q = 0; q < 8; ++q) {
            float w = useW ? edgeW(er[q]) : 1.f;
#pragma unroll
            for (int k = 0; k < 8; ++k) a[k] += xf[q][k] * w;
        }
    }
    if (j + 4 <= end) {
        int2 er[4];
#pragma unroll
        for (int q = 0; q < 4; ++q) er[q] = edges[j + q];
        float xf[4][8];
#pragma unroll
        for (int q = 0; q < 4; ++q) ld8v(base + (size_t)er[q].x * D, xf[q]);
#pragma unroll
        for (int q = 0; q < 4; ++q) {
            float w = useW ? edgeW(er[q]) : 1.f;
#pragma unroll
            for (int k = 0; k < 8; ++k) a[k] += xf[q][k] * w;
        }
        j += 4;
    }
    for (; j < end; ++j) {
        int2 er = edges[j];
        float w = useW ? edgeW(er) : 1.f;
        float xv[8];
        ld8v(base + (size_t)er.x * D, xv);
#pragma unroll
        for (int k = 0; k < 8; ++k) a[k] += xv[k] * w;
    }
    if (dstScale) {
        float sc = dstScale[v];
#pragma unroll
        for (int k = 0; k < 8; ++k) a[k] = a[k] * sc + bias[c8 + k];
    }
    if (relu) {
#pragma unroll
        for (int k = 0; k < 8; ++k) a[k] = fmaxf(a[k], 0.f);
    }
    st8f(out + (size_t)v * D + c8, a);
}

// ---------------- final agg: D=4, fp32 ----------------
__global__ void agg4_kernel(const float* __restrict__ in, float* __restrict__ out,
                            const int* __restrict__ rowStart, const int2* __restrict__ edges,
                            const float* __restrict__ dstScale, const float* __restrict__ bias,
                            int N) {
    int v = blockIdx.x * blockDim.x + threadIdx.x;
    if (v >= N) return;
    int beg = rowStart[v], end = rowStart[v + 1];
    float ax = 0.f, ay = 0.f, az = 0.f, aw = 0.f;
    for (int j = beg; j < end; ++j) {
        int2 er = edges[j];
        float4 val = ld4f(in + (size_t)er.x * 4);
        ax += val.x; ay += val.y; az += val.z; aw += val.w;
    }
    float sc = dstScale[v];
    ax = ax * sc + bias[0];
    ay = ay * sc + bias[1];
    az = az * sc + bias[2];
    aw = aw * sc + bias[3];
    st4f(out + (size_t)v * 4, make_float4(ax, ay, az, aw));
}

// ---------------- tiled GEMM with v_dot2_f32_f16 (fp16 pairs, fp32 accumulate) ------
template <int KT, int RPT, int TN>
__global__ __launch_bounds__(256) void gemm_tiled(
    const __half* __restrict__ A, const float* __restrict__ W,
    const float* __restrict__ rowScaleIn,   // null -> 1
    const float* __restrict__ rowScaleOut,  // null -> no scale/bias
    const float* __restrict__ bias,
    __half* __restrict__ C, int N, int K1, int relu)
{
    constexpr int NC8 = TN / 8;
    constexpr int RT  = 256 / NC8;
    constexpr int TM  = RT * RPT;
    constexpr int AFPT = TM * KT / 256;   // A halves per thread per stage
    constexpr int KP  = KT / 2;
    static_assert(AFPT == 2 || AFPT == 8, "unexpected AFPT");

    __shared__ h2v Alds[KP][TM];          // (A[row][2kp], A[row][2kp+1])
    __shared__ h2v Wlds[KP][TN];          // (W[2kp][c],  W[2kp+1][c])

    const int t    = threadIdx.x;
    const int cg   = t % NC8;
    const int rt   = t / NC8;
    const int c0   = cg * 8;
    const int row0 = blockIdx.x * TM;

    const int arow   = t % TM;
    const int akb    = (t / TM) * AFPT;   // even (AFPT is 2 or 8)
    const int arow_g = row0 + arow;
    float rsc = 1.0f;
    if (rowScaleIn && arow_g < N) rsc = rowScaleIn[arow_g];

    float acc[RPT][8];
#pragma unroll
    for (int r = 0; r < RPT; ++r)
#pragma unroll
        for (int j = 0; j < 8; ++j) acc[r][j] = 0.f;

    for (int k0 = 0; k0 < K1; k0 += KT) {
        // ---- stage A: fp16 load, scale in fp32, pack k-pairs ----
        float av[AFPT];
        if (arow_g < N) {
            const __half* ag = A + (size_t)arow_g * K1 + k0 + akb;
            if constexpr (AFPT == 8) ld8v(ag, av);
            else                     ld2v(ag, av);
        } else {
#pragma unroll
            for (int j = 0; j < AFPT; ++j) av[j] = 0.f;
        }
#pragma unroll
        for (int j = 0; j < AFPT; j += 2)
            Alds[(akb + j) >> 1][arow] = packh2(av[j] * rsc, av[j + 1] * rsc);

        // ---- stage W: pack k-pairs from two fp32 rows ----
        for (int i = t; i < KP * TN; i += 256) {
            int kp = i / TN, c = i % TN;
            Wlds[kp][c] = packh2(W[(size_t)(k0 + 2 * kp) * TN + c],
                                 W[(size_t)(k0 + 2 * kp + 1) * TN + c]);
        }
        __syncthreads();

#pragma unroll
        for (int kp = 0; kp < KP; ++kp) {
            h2v a2[RPT];
            if constexpr (RPT == 4) {
                union { float4 f; h2v h[4]; } u;
                u.f = *(const float4*)&Alds[kp][rt * 4];
                a2[0] = u.h[0]; a2[1] = u.h[1]; a2[2] = u.h[2]; a2[3] = u.h[3];
            } else if constexpr (RPT == 2) {
                union { float2 f; h2v h[2]; } u;
                u.f = *(const float2*)&Alds[kp][rt * 2];
                a2[0] = u.h[0]; a2[1] = u.h[1];
            } else {
                a2[0] = Alds[kp][rt];
            }
            union { float4 f; h2v h[4]; } w0, w1;
            w0.f = *(const float4*)&Wlds[kp][c0];
            w1.f = *(const float4*)&Wlds[kp][c0 + 4];
#pragma unroll
            for (int r = 0; r < RPT; ++r) {
                acc[r][0] = __builtin_amdgcn_fdot2(a2[r], w0.h[0], acc[r][0], false);
                acc[r][1] = __builtin_amdgcn_fdot2(a2[r], w0.h[1], acc[r][1], false);
                acc[r][2] = __builtin_amdgcn_fdot2(a2[r], w0.h[2], acc[r][2], false);
                acc[r][3] = __builtin_amdgcn_fdot2(a2[r], w0.h[3], acc[r][3], false);
                acc[r][4] = __builtin_amdgcn_fdot2(a2[r], w1.h[0], acc[r][4], false);
                acc[r][5] = __builtin_amdgcn_fdot2(a2[r], w1.h[1], acc[r][5], false);
                acc[r][6] = __builtin_amdgcn_fdot2(a2[r], w1.h[2], acc[r][6], false);
                acc[r][7] = __builtin_amdgcn_fdot2(a2[r], w1.h[3], acc[r][7], false);
            }
        }
        __syncthreads();
    }

#pragma unroll
    for (int r = 0; r < RPT; ++r) {
        int row_g = row0 + rt * RPT + r;
        if (row_g >= N) continue;
        float f[8];
        if (rowScaleOut) {
            float sc = rowScaleOut[row_g];
#pragma unroll
            for (int j = 0; j < 8; ++j) f[j] = acc[r][j] * sc + bias[c0 + j];
        } else {
#pragma unroll
            for (int j = 0; j < 8; ++j) f[j] = acc[r][j];
        }
        if (relu) {
#pragma unroll
            for (int j = 0; j < 8; ++j) f[j] = fmaxf(f[j], 0.f);
        }
        st8f(C + (size_t)row_g * TN + c0, f);
    }
}

// ---------------- naive GEMM (K2=4 layer) ----------------
__global__ void gemm_naive(const __half* __restrict__ A, const float* __restrict__ W,
                           const float* __restrict__ rowScaleIn,
                           float* __restrict__ C, int N, int K1, int K2) {
    int gid = blockIdx.x * blockDim.x + threadIdx.x;
    int col = gid % K2;
    int row = gid / K2;
    if (row >= N) return;
    const __half* a = A + (size_t)row * K1;
    float acc = 0.0f;
    for (int k = 0; k < K1; ++k) acc += (float)a[k] * W[k * K2 + col];
    if (rowScaleIn) acc *= rowScaleIn[row];
    C[gid] = acc;
}

static inline int nblk(long n) { return (int)((n + BLOCK - 1) / BLOCK); }

extern "C" void kernel_launch(void* const* d_in, const int* in_sizes, int n_in,
                              void* d_out, int out_size, void* d_ws, size_t ws_size,
                              hipStream_t stream) {
    const float* x    = (const float*)d_in[0];
    const float* efet = (const float*)d_in[1];
    const int*   src  = (const int*)d_in[2];
    const int*   dst  = (const int*)d_in[3];
    const float* W1 = (const float*)d_in[4];  const float* b1 = (const float*)d_in[5];
    const float* W2 = (const float*)d_in[6];  const float* b2 = (const float*)d_in[7];
    const float* W3 = (const float*)d_in[8];  const float* b3 = (const float*)d_in[9];
    const float* W4 = (const float*)d_in[10]; const float* b4 = (const float*)d_in[11];
    const float* W5 = (const float*)d_in[12]; const float* b5 = (const float*)d_in[13];
    float* out = (float*)d_out;

    const int N = in_sizes[0] / 16;
    const int E = in_sizes[2];
    const int NB1024 = (N + 1023) / 1024;

    // ---- workspace layout ----
    float* fws = (float*)d_ws;
    size_t o = 0;
    auto alloc = [&](size_t nf) { float* p = fws + o; o += (nf + 3) & ~(size_t)3; return p; };
    float*  normO     = alloc(N);
    float*  normI     = alloc(N);
    int*    rowStart  = (int*)alloc(N + 1);
    int*    blockSums = (int*)alloc(64);
    int2*   edges     = (int2*)alloc(2 * (size_t)E);     // 8B per edge
    int*    degOpad   = (int*)alloc((size_t)PAD * N);    // zeroed
    int*    degIpad   = (int*)alloc((size_t)PAD * N);    // zeroed
    int*    cursorPad = (int*)alloc((size_t)PAD * N);    // init by scan_add_norm
    __half* xh        = (__half*)alloc(8 * (size_t)N);   // N x 16 halves
    __half* bufA      = (__half*)alloc(128 * (size_t)N); // 256N halves
    __half* bufB      = (__half*)alloc(128 * (size_t)N); // 256N halves
    __half* bufC      = (__half*)alloc(64 * (size_t)N);  // 128N halves
    float*  t5f       = (float*)bufA;                    // layer-5 fp32 temp (aliases bufA)

    // ---- degrees + CSR build ----
    hipMemsetAsync(degOpad, 0, 2 * (size_t)PAD * N * sizeof(int), stream);
    deg_kernel<<<nblk(E), BLOCK, 0, stream>>>(src, dst, degOpad, degIpad, E);
    scan_local<<<NB1024, 1024, 0, stream>>>(degIpad, rowStart, blockSums, N);
    scan_sums<<<1, 64, 0, stream>>>(blockSums, NB1024);
    scan_add_norm<<<nblk(N + 1), BLOCK, 0, stream>>>(rowStart, blockSums, cursorPad,
                                                     degOpad, degIpad, normO, normI, N, E);
    cvt_x<<<nblk((long)N * 4), BLOCK, 0, stream>>>(x, normO, xh, N);
    permute_kernel<<<nblk(E), BLOCK, 0, stream>>>(src, dst, efet, cursorPad, edges, E);

    // ---- Layer 1: agg16 (fp16, normO folded) -> GEMM 16->256 -> ewa256 ----
    agg8_kernel<16><<<nblk((long)N * 2), BLOCK, 0, stream>>>(
        xh, bufC, rowStart, edges, 0, nullptr, nullptr, N, 0);
    gemm_tiled<16, 4, 256><<<(N + 31) / 32, 256, 0, stream>>>(
        bufC, W1, nullptr, normI, b1, bufA, N, 16, 1);
    agg8_kernel<256><<<nblk((long)N * 32), BLOCK, 0, stream>>>(
        bufA, bufB, rowStart, edges, 1, nullptr, nullptr, N, 1);   // h1 = bufB

    // ---- Layer 2: GEMM 256->128, gc128, ewa128 ----
    gemm_tiled<32, 4, 128><<<(N + 63) / 64, 256, 0, stream>>>(
        bufB, W2, normO, nullptr, nullptr, bufA, N, 256, 0);
    agg8_kernel<128><<<nblk((long)N * 16), BLOCK, 0, stream>>>(
        bufA, bufC, rowStart, edges, 0, normI, b2, N, 1);
    agg8_kernel<128><<<nblk((long)N * 16), BLOCK, 0, stream>>>(
        bufC, bufB, rowStart, edges, 1, nullptr, nullptr, N, 1);   // h2 = bufB

    // ---- Layer 3: GEMM 128->64, gc64, ewa64 ----
    gemm_tiled<32, 2, 64><<<(N + 63) / 64, 256, 0, stream>>>(
        bufB, W3, normO, nullptr, nullptr, bufA, N, 128, 0);
    agg8_kernel<64><<<nblk((long)N * 8), BLOCK, 0, stream>>>(
        bufA, bufC, rowStart, edges, 0, normI, b3, N, 1);
    agg8_kernel<64><<<nblk((long)N * 8), BLOCK, 0, stream>>>(
        bufC, bufB, rowStart, edges, 1, nullptr, nullptr, N, 1);   // h3 = bufB

    // ---- Layer 4: GEMM 64->32, gc32 -> h4 ----
    gemm_tiled<32, 1, 32><<<(N + 63) / 64, 256, 0, stream>>>(
        bufB, W4, normO, nullptr, nullptr, bufA, N, 64, 0);
    agg8_kernel<32><<<nblk((long)N * 4), BLOCK, 0, stream>>>(
        bufA, bufB, rowStart, edges, 0, normI, b4, N, 1);          // h4 = bufB

    // ---- Layer 5: GEMM 32->4 (fp32 out), agg4 -> out ----
    gemm_naive<<<nblk((long)N * 4), BLOCK, 0, stream>>>(
        bufB, W5, normO, t5f, N, 32, 4);
    agg4_kernel<<<nblk((long)N), BLOCK, 0, stream>>>(
        t5f, out, rowStart, edges, normI, b5, N);
}

// Round 13
// 509.760 us; speedup vs baseline: 1.1296x; 1.0294x over previous
//
#include <hip/hip_runtime.h>
#include <hip/hip_fp16.h>

#define BLOCK 256
#define PAD 16   // one counter per 64B cache line

typedef _Float16 h2v __attribute__((ext_vector_type(2)));

// ---------------- helpers ----------------
__device__ inline void st4f(__half* p, float4 v) {
    __half2 a = __floats2half2_rn(v.x, v.y);
    __half2 b = __floats2half2_rn(v.z, v.w);
    uint2 u;
    u.x = *reinterpret_cast<unsigned*>(&a);
    u.y = *reinterpret_cast<unsigned*>(&b);
    *(uint2*)p = u;
}
__device__ inline void st4f(float* p, float4 v) { *(float4*)p = v; }
__device__ inline void st8f(float* p, const float f[8]) {
    *(float4*)p       = make_float4(f[0], f[1], f[2], f[3]);
    *(float4*)(p + 4) = make_float4(f[4], f[5], f[6], f[7]);
}
__device__ inline void st8f(__half* p, const float f[8]) {
    union { __half2 h[4]; float4 v; } u;
    u.h[0] = __floats2half2_rn(f[0], f[1]);
    u.h[1] = __floats2half2_rn(f[2], f[3]);
    u.h[2] = __floats2half2_rn(f[4], f[5]);
    u.h[3] = __floats2half2_rn(f[6], f[7]);
    *(float4*)p = u.v;
}
__device__ inline void ld2v(const __half* p, float* f) {
    float2 v = __half22float2(*(const __half2*)p); f[0] = v.x; f[1] = v.y;
}
__device__ inline void ld8v(const __half* p, float* f) {
    float4 r = *(const float4*)p;
    const __half2* h = (const __half2*)&r;
#pragma unroll
    for (int j = 0; j < 4; ++j) {
        float2 fj = __half22float2(h[j]);
        f[2*j] = fj.x; f[2*j+1] = fj.y;
    }
}
__device__ inline float4 ld4f(const float* p) { return *(const float4*)p; }
__device__ inline float edgeW(int2 er) {
    return __half2float(__ushort_as_half((unsigned short)(er.y & 0xffff)));
}
__device__ inline h2v packh2(float a, float b) {
    h2v r; r.x = (_Float16)a; r.y = (_Float16)b; return r;
}

// ---------------- degree (padded counters, int atomics) ----------------
__global__ void deg_kernel(const int* __restrict__ src, const int* __restrict__ dst,
                           int* __restrict__ degOpad, int* __restrict__ degIpad, int E) {
    int e = blockIdx.x * blockDim.x + threadIdx.x;
    if (e < E) {
        atomicAdd(&degOpad[src[e] * PAD], 1);
        atomicAdd(&degIpad[dst[e] * PAD], 1);
    }
}

// ---------------- block-local exclusive scan of degI ----------------
__global__ void scan_local(const int* __restrict__ degIpad, int* __restrict__ rowStart,
                           int* __restrict__ blockSums, int N) {
    __shared__ int tmp[1024];
    int tid = threadIdx.x;
    int i = blockIdx.x * 1024 + tid;
    int v = (i < N) ? degIpad[i * PAD] : 0;
    tmp[tid] = v;
    __syncthreads();
    for (int off = 1; off < 1024; off <<= 1) {
        int t = (tid >= off) ? tmp[tid - off] : 0;
        __syncthreads();
        tmp[tid] += t;
        __syncthreads();
    }
    if (i < N) rowStart[i] = tmp[tid] - v;
    if (tid == 0) blockSums[blockIdx.x] = tmp[1023];
}

// ---------------- finalize: block-sum scan + rowStart/cursor/norms + x->fp16 ----------
// grid covers 4N threads (cvt part); rowStart part uses gid<=N.
__global__ void finalize_kernel(int* __restrict__ rowStart, const int* __restrict__ blockSums,
                                int nb, int* __restrict__ cursorPad,
                                const int* __restrict__ degOpad, const int* __restrict__ degIpad,
                                float* __restrict__ normO, float* __restrict__ normI,
                                const float* __restrict__ x, __half* __restrict__ xh,
                                int N, int E) {
    __shared__ int soff[64];
    int t = threadIdx.x;
    if (t < 64) {
        int acc = 0;
        for (int k = 0; k < t && k < nb; ++k) acc += blockSums[k];
        soff[t] = acc;
    }
    __syncthreads();
    int gid = blockIdx.x * blockDim.x + t;
    if (gid < N) {
        int r = rowStart[gid] + soff[gid >> 10];
        rowStart[gid] = r;
        cursorPad[gid * PAD] = r;
        normO[gid] = rsqrtf(fmaxf((float)degOpad[gid * PAD], 1.0f));
        normI[gid] = rsqrtf(fmaxf((float)degIpad[gid * PAD], 1.0f));
    }
    if (gid == N) rowStart[N] = E;
    int v = gid >> 2, c = (gid & 3) * 4;
    if (v < N) {
        float4 f = ld4f(x + (size_t)v * 16 + c);
        float w = rsqrtf(fmaxf((float)degOpad[v * PAD], 1.0f));
        f.x *= w; f.y *= w; f.z *= w; f.w *= w;
        st4f(xh + (size_t)v * 16 + c, f);
    }
}

// ---------------- permute edges into dst-sorted order: one 8B record ----------------
__global__ void permute_kernel(const int* __restrict__ src, const int* __restrict__ dst,
                               const float* __restrict__ efet, int* __restrict__ cursorPad,
                               int2* __restrict__ edges, int E) {
    int e = blockIdx.x * blockDim.x + threadIdx.x;
    if (e < E) {
        int d = dst[e];
        int p = atomicAdd(&cursorPad[d * PAD], 1);
        int2 er;
        er.x = src[e];
        er.y = (int)__half_as_ushort(__float2half(efet[e]));
        edges[p] = er;
    }
}

// ---------------- CSR gather-agg, 8 cols/thread, batched raw loads for MLP ----------
// Loads are staged into raw[] float4 arrays (NO conversion in the load loop) so the
// compiler issues 8 back-to-back global_load_dwordx4 with graduated vmcnt.
template <int D>
__global__ __launch_bounds__(256) void agg8_kernel(
    const __half* __restrict__ in, __half* __restrict__ out,
    const int* __restrict__ rowStart, const int2* __restrict__ edges,
    int useW,
    const float* __restrict__ dstScale,   // null -> skip scale+bias
    const float* __restrict__ bias,
    int N, int relu) {
    constexpr int TPN = D / 8;
    int gid = blockIdx.x * blockDim.x + threadIdx.x;
    int v = gid / TPN;
    int c8 = (gid % TPN) * 8;
    if (v >= N) return;
    int beg = rowStart[v], end = rowStart[v + 1];
    float a[8];
#pragma unroll
    for (int k = 0; k < 8; ++k) a[k] = 0.f;
    const __half* base = in + c8;

    int j = beg;
    for (; j + 8 <= end; j += 8) {
        int2 er[8];
#pragma unroll
        for (int q = 0; q < 8; ++q) er[q] = edges[j + q];
        float4 raw[8];
#pragma unroll
        for (int q = 0; q < 8; ++q) raw[q] = *(const float4*)(base + (size_t)er[q].x * D);
#pragma unroll
        for (int q = 0; q < 8; ++q) {
            float w = useW ? edgeW(er[q]) : 1.f;
            const __half2* h = (const __half2*)&raw[q];
#pragma unroll
            for (int p = 0; p < 4; ++p) {
                float2 fj = __half22float2(h[p]);
                a[2*p]   += fj.x * w;
                a[2*p+1] += fj.y * w;
            }
        }
    }
    if (j + 4 <= end) {
        int2 er[4];
#pragma unroll
        for (int q = 0; q < 4; ++q) er[q] = edges[j + q];
        float4 raw[4];
#pragma unroll
        for (int q = 0; q < 4; ++q) raw[q] = *(const float4*)(base + (size_t)er[q].x * D);
#pragma unroll
        for (int q = 0; q < 4; ++q) {
            float w = useW ? edgeW(er[q]) : 1.f;
            const __half2* h = (const __half2*)&raw[q];
#pragma unroll
            for (int p = 0; p < 4; ++p) {
                float2 fj = __half22float2(h[p]);
                a[2*p]   += fj.x * w;
                a[2*p+1] += fj.y * w;
            }
        }
        j += 4;
    }
    for (; j < end; ++j) {
        int2 er = edges[j];
        float w = useW ? edgeW(er) : 1.f;
        float xv[8];
        ld8v(base + (size_t)er.x * D, xv);
#pragma unroll
        for (int k = 0; k < 8; ++k) a[k] += xv[k] * w;
    }
    if (dstScale) {
        float sc = dstScale[v];
#pragma unroll
        for (int k = 0; k < 8; ++k) a[k] = a[k] * sc + bias[c8 + k];
    }
    if (relu) {
#pragma unroll
        for (int k = 0; k < 8; ++k) a[k] = fmaxf(a[k], 0.f);
    }
    st8f(out + (size_t)v * D + c8, a);
}

// ---------------- gc32 fused with 32->4 GEMM (W5) ----------------
// t5[v] = normO[v] * (relu(agg(m4)[v]*normI[v] + b4) @ W5)
__global__ __launch_bounds__(256) void gc32_fused(
    const __half* __restrict__ in, float* __restrict__ t5,
    const int* __restrict__ rowStart, const int2* __restrict__ edges,
    const float* __restrict__ normI, const float* __restrict__ b4,
    const float* __restrict__ normO, const float* __restrict__ W5,
    int N) {
    int gid = blockIdx.x * blockDim.x + threadIdx.x;
    int v = gid >> 2;
    int q = gid & 3;
    int c8 = q * 8;
    if (v >= N) return;
    int beg = rowStart[v], end = rowStart[v + 1];
    float a[8];
#pragma unroll
    for (int k = 0; k < 8; ++k) a[k] = 0.f;
    const __half* base = in + c8;

    int j = beg;
    for (; j + 8 <= end; j += 8) {
        int2 er[8];
#pragma unroll
        for (int p = 0; p < 8; ++p) er[p] = edges[j + p];
        float4 raw[8];
#pragma unroll
        for (int p = 0; p < 8; ++p) raw[p] = *(const float4*)(base + (size_t)er[p].x * 32);
#pragma unroll
        for (int p = 0; p < 8; ++p) {
            const __half2* h = (const __half2*)&raw[p];
#pragma unroll
            for (int s = 0; s < 4; ++s) {
                float2 fj = __half22float2(h[s]);
                a[2*s]   += fj.x;
                a[2*s+1] += fj.y;
            }
        }
    }
    for (; j < end; ++j) {
        int2 er = edges[j];
        float xv[8];
        ld8v(base + (size_t)er.x * 32, xv);
#pragma unroll
        for (int k = 0; k < 8; ++k) a[k] += xv[k];
    }
    float sc = normI[v];
#pragma unroll
    for (int k = 0; k < 8; ++k) a[k] = fmaxf(a[k] * sc + b4[c8 + k], 0.f);

    float p4[4] = {0.f, 0.f, 0.f, 0.f};
#pragma unroll
    for (int k = 0; k < 8; ++k) {
        float4 wr = ld4f(W5 + (size_t)(c8 + k) * 4);
        p4[0] += a[k] * wr.x; p4[1] += a[k] * wr.y;
        p4[2] += a[k] * wr.z; p4[3] += a[k] * wr.w;
    }
#pragma unroll
    for (int c = 0; c < 4; ++c) {
        p4[c] += __shfl_xor(p4[c], 1);
        p4[c] += __shfl_xor(p4[c], 2);
    }
    if (q == 0) {
        float no = normO[v];
        st4f(t5 + (size_t)v * 4, make_float4(p4[0]*no, p4[1]*no, p4[2]*no, p4[3]*no));
    }
}

// ---------------- final agg: D=4, fp32, batched loads ----------------
__global__ void agg4_kernel(const float* __restrict__ in, float* __restrict__ out,
                            const int* __restrict__ rowStart, const int2* __restrict__ edges,
                            const float* __restrict__ dstScale, const float* __restrict__ bias,
                            int N) {
    int v = blockIdx.x * blockDim.x + threadIdx.x;
    if (v >= N) return;
    int beg = rowStart[v], end = rowStart[v + 1];
    float ax = 0.f, ay = 0.f, az = 0.f, aw = 0.f;
    int j = beg;
    for (; j + 4 <= end; j += 4) {
        int2 er[4];
#pragma unroll
        for (int q = 0; q < 4; ++q) er[q] = edges[j + q];
        float4 raw[4];
#pragma unroll
        for (int q = 0; q < 4; ++q) raw[q] = ld4f(in + (size_t)er[q].x * 4);
#pragma unroll
        for (int q = 0; q < 4; ++q) {
            ax += raw[q].x; ay += raw[q].y; az += raw[q].z; aw += raw[q].w;
        }
    }
    for (; j < end; ++j) {
        float4 val = ld4f(in + (size_t)edges[j].x * 4);
        ax += val.x; ay += val.y; az += val.z; aw += val.w;
    }
    float sc = dstScale[v];
    ax = ax * sc + bias[0];
    ay = ay * sc + bias[1];
    az = az * sc + bias[2];
    aw = aw * sc + bias[3];
    st4f(out + (size_t)v * 4, make_float4(ax, ay, az, aw));
}

// ---------------- tiled GEMM with v_dot2_f32_f16 (fp16 pairs, fp32 accumulate) ------
template <int KT, int RPT, int TN>
__global__ __launch_bounds__(256) void gemm_tiled(
    const __half* __restrict__ A, const float* __restrict__ W,
    const float* __restrict__ rowScaleIn,   // null -> 1
    const float* __restrict__ rowScaleOut,  // null -> no scale/bias
    const float* __restrict__ bias,
    __half* __restrict__ C, int N, int K1, int relu)
{
    constexpr int NC8 = TN / 8;
    constexpr int RT  = 256 / NC8;
    constexpr int TM  = RT * RPT;
    constexpr int AFPT = TM * KT / 256;
    constexpr int KP  = KT / 2;
    static_assert(AFPT == 2 || AFPT == 8, "unexpected AFPT");

    __shared__ h2v Alds[KP][TM];
    __shared__ h2v Wlds[KP][TN];

    const int t    = threadIdx.x;
    const int cg   = t % NC8;
    const int rt   = t / NC8;
    const int c0   = cg * 8;
    const int row0 = blockIdx.x * TM;

    const int arow   = t % TM;
    const int akb    = (t / TM) * AFPT;
    const int arow_g = row0 + arow;
    float rsc = 1.0f;
    if (rowScaleIn && arow_g < N) rsc = rowScaleIn[arow_g];

    float acc[RPT][8];
#pragma unroll
    for (int r = 0; r < RPT; ++r)
#pragma unroll
        for (int j = 0; j < 8; ++j) acc[r][j] = 0.f;

    for (int k0 = 0; k0 < K1; k0 += KT) {
        float av[AFPT];
        if (arow_g < N) {
            const __half* ag = A + (size_t)arow_g * K1 + k0 + akb;
            if constexpr (AFPT == 8) ld8v(ag, av);
            else                     ld2v(ag, av);
        } else {
#pragma unroll
            for (int j = 0; j < AFPT; ++j) av[j] = 0.f;
        }
#pragma unroll
        for (int j = 0; j < AFPT; j += 2)
            Alds[(akb + j) >> 1][arow] = packh2(av[j] * rsc, av[j + 1] * rsc);

        for (int i = t; i < KP * TN; i += 256) {
            int kp = i / TN, c = i % TN;
            Wlds[kp][c] = packh2(W[(size_t)(k0 + 2 * kp) * TN + c],
                                 W[(size_t)(k0 + 2 * kp + 1) * TN + c]);
        }
        __syncthreads();

#pragma unroll
        for (int kp = 0; kp < KP; ++kp) {
            h2v a2[RPT];
            if constexpr (RPT == 4) {
                union { float4 f; h2v h[4]; } u;
                u.f = *(const float4*)&Alds[kp][rt * 4];
                a2[0] = u.h[0]; a2[1] = u.h[1]; a2[2] = u.h[2]; a2[3] = u.h[3];
            } else if constexpr (RPT == 2) {
                union { float2 f; h2v h[2]; } u;
                u.f = *(const float2*)&Alds[kp][rt * 2];
                a2[0] = u.h[0]; a2[1] = u.h[1];
            } else {
                a2[0] = Alds[kp][rt];
            }
            union { float4 f; h2v h[4]; } w0, w1;
            w0.f = *(const float4*)&Wlds[kp][c0];
            w1.f = *(const float4*)&Wlds[kp][c0 + 4];
#pragma unroll
            for (int r = 0; r < RPT; ++r) {
                acc[r][0] = __builtin_amdgcn_fdot2(a2[r], w0.h[0], acc[r][0], false);
                acc[r][1] = __builtin_amdgcn_fdot2(a2[r], w0.h[1], acc[r][1], false);
                acc[r][2] = __builtin_amdgcn_fdot2(a2[r], w0.h[2], acc[r][2], false);
                acc[r][3] = __builtin_amdgcn_fdot2(a2[r], w0.h[3], acc[r][3], false);
                acc[r][4] = __builtin_amdgcn_fdot2(a2[r], w1.h[0], acc[r][4], false);
                acc[r][5] = __builtin_amdgcn_fdot2(a2[r], w1.h[1], acc[r][5], false);
                acc[r][6] = __builtin_amdgcn_fdot2(a2[r], w1.h[2], acc[r][6], false);
                acc[r][7] = __builtin_amdgcn_fdot2(a2[r], w1.h[3], acc[r][7], false);
            }
        }
        __syncthreads();
    }

#pragma unroll
    for (int r = 0; r < RPT; ++r) {
        int row_g = row0 + rt * RPT + r;
        if (row_g >= N) continue;
        float f[8];
        if (rowScaleOut) {
            float sc = rowScaleOut[row_g];
#pragma unroll
            for (int j = 0; j < 8; ++j) f[j] = acc[r][j] * sc + bias[c0 + j];
        } else {
#pragma unroll
            for (int j = 0; j < 8; ++j) f[j] = acc[r][j];
        }
        if (relu) {
#pragma unroll
            for (int j = 0; j < 8; ++j) f[j] = fmaxf(f[j], 0.f);
        }
        st8f(C + (size_t)row_g * TN + c0, f);
    }
}

static inline int nblk(long n) { return (int)((n + BLOCK - 1) / BLOCK); }

extern "C" void kernel_launch(void* const* d_in, const int* in_sizes, int n_in,
                              void* d_out, int out_size, void* d_ws, size_t ws_size,
                              hipStream_t stream) {
    const float* x    = (const float*)d_in[0];
    const float* efet = (const float*)d_in[1];
    const int*   src  = (const int*)d_in[2];
    const int*   dst  = (const int*)d_in[3];
    const float* W1 = (const float*)d_in[4];  const float* b1 = (const float*)d_in[5];
    const float* W2 = (const float*)d_in[6];  const float* b2 = (const float*)d_in[7];
    const float* W3 = (const float*)d_in[8];  const float* b3 = (const float*)d_in[9];
    const float* W4 = (const float*)d_in[10]; const float* b4 = (const float*)d_in[11];
    const float* W5 = (const float*)d_in[12]; const float* b5 = (const float*)d_in[13];
    float* out = (float*)d_out;

    const int N = in_sizes[0] / 16;
    const int E = in_sizes[2];
    const int NB1024 = (N + 1023) / 1024;

    // ---- workspace layout ----
    float* fws = (float*)d_ws;
    size_t o = 0;
    auto alloc = [&](size_t nf) { float* p = fws + o; o += (nf + 3) & ~(size_t)3; return p; };
    float*  normO     = alloc(N);
    float*  normI     = alloc(N);
    int*    rowStart  = (int*)alloc(N + 1);
    int*    blockSums = (int*)alloc(64);
    int2*   edges     = (int2*)alloc(2 * (size_t)E);     // 8B per edge
    int*    degOpad   = (int*)alloc((size_t)PAD * N);    // zeroed
    int*    degIpad   = (int*)alloc((size_t)PAD * N);    // zeroed
    int*    cursorPad = (int*)alloc((size_t)PAD * N);    // init by finalize
    __half* xh        = (__half*)alloc(8 * (size_t)N);   // N x 16 halves
    __half* bufA      = (__half*)alloc(128 * (size_t)N); // 256N halves
    __half* bufB      = (__half*)alloc(128 * (size_t)N); // 256N halves
    __half* bufC      = (__half*)alloc(64 * (size_t)N);  // 128N halves
    float*  t5f       = (float*)bufB;                    // layer-5 fp32 temp (aliases bufB; m4 lives in bufA)

    // ---- degrees + CSR build ----
    hipMemsetAsync(degOpad, 0, 2 * (size_t)PAD * N * sizeof(int), stream);
    deg_kernel<<<nblk(E), BLOCK, 0, stream>>>(src, dst, degOpad, degIpad, E);
    scan_local<<<NB1024, 1024, 0, stream>>>(degIpad, rowStart, blockSums, N);
    finalize_kernel<<<nblk(4L * N), BLOCK, 0, stream>>>(rowStart, blockSums, NB1024, cursorPad,
                                                        degOpad, degIpad, normO, normI,
                                                        x, xh, N, E);
    permute_kernel<<<nblk(E), BLOCK, 0, stream>>>(src, dst, efet, cursorPad, edges, E);

    // ---- Layer 1: agg16 (fp16, normO folded) -> GEMM 16->256 -> ewa256 ----
    agg8_kernel<16><<<nblk((long)N * 2), BLOCK, 0, stream>>>(
        xh, bufC, rowStart, edges, 0, nullptr, nullptr, N, 0);
    gemm_tiled<16, 4, 256><<<(N + 31) / 32, 256, 0, stream>>>(
        bufC, W1, nullptr, normI, b1, bufA, N, 16, 1);
    agg8_kernel<256><<<nblk((long)N * 32), BLOCK, 0, stream>>>(
        bufA, bufB, rowStart, edges, 1, nullptr, nullptr, N, 1);   // h1 = bufB

    // ---- Layer 2: GEMM 256->128, gc128, ewa128 ----
    gemm_tiled<32, 4, 128><<<(N + 63) / 64, 256, 0, stream>>>(
        bufB, W2, normO, nullptr, nullptr, bufA, N, 256, 0);
    agg8_kernel<128><<<nblk((long)N * 16), BLOCK, 0, stream>>>(
        bufA, bufC, rowStart, edges, 0, normI, b2, N, 1);
    agg8_kernel<128><<<nblk((long)N * 16), BLOCK, 0, stream>>>(
        bufC, bufB, rowStart, edges, 1, nullptr, nullptr, N, 1);   // h2 = bufB

    // ---- Layer 3: GEMM 128->64, gc64, ewa64 ----
    gemm_tiled<32, 2, 64><<<(N + 63) / 64, 256, 0, stream>>>(
        bufB, W3, normO, nullptr, nullptr, bufA, N, 128, 0);
    agg8_kernel<64><<<nblk((long)N * 8), BLOCK, 0, stream>>>(
        bufA, bufC, rowStart, edges, 0, normI, b3, N, 1);
    agg8_kernel<64><<<nblk((long)N * 8), BLOCK, 0, stream>>>(
        bufC, bufB, rowStart, edges, 1, nullptr, nullptr, N, 1);   // h3 = bufB

    // ---- Layer 4: GEMM 64->32 -> m4 (bufA), gc32 fused w/ 32->4 GEMM -> t5f (bufB) ----
    gemm_tiled<32, 1, 32><<<(N + 63) / 64, 256, 0, stream>>>(
        bufB, W4, normO, nullptr, nullptr, bufA, N, 64, 0);
    gc32_fused<<<nblk((long)N * 4), BLOCK, 0, stream>>>(
        bufA, t5f, rowStart, edges, normI, b4, normO, W5, N);

    // ---- Layer 5: agg4 -> out ----
    agg4_kernel<<<nblk((long)N), BLOCK, 0, stream>>>(
        t5f, out, rowStart, edges, normI, b5, N);
}